// Round 21
// baseline (23.442 us; speedup 1.0000x reference)
//
#include <hip/hip_runtime.h>

#define BS 4
#define DM 1024
#define LL 2048
#define NS 64
#define CC 32        // chunks
#define TT 64        // chunk length
#define PAD 68       // LDS row stride for 64-wide mats (136B -> conflict-light)
#define UPAD 2060    // U row stride (shorts): dword stride 1030 -> spread banks
#define DT 16        // d-rows per block

typedef __attribute__((ext_vector_type(8))) short bf8;     // 8 bf16 (4 VGPR)
typedef __attribute__((ext_vector_type(4))) float f32x4;   // mfma C/D

__device__ __forceinline__ unsigned short f2bf(float x) {  // fp32 -> bf16 RNE
    unsigned u = __float_as_uint(x);
    return (unsigned short)((u + 0x7FFFu + ((u >> 16) & 1u)) >> 16);
}

__device__ __forceinline__ bf8 ld_frag(const short* p) {   // 8 contiguous bf16 (8B aligned)
    short4 a = *(const short4*)p;
    short4 b = *(const short4*)(p + 4);
    bf8 f;
    f[0]=a.x; f[1]=a.y; f[2]=a.z; f[3]=a.w;
    f[4]=b.x; f[5]=b.y; f[6]=b.z; f[7]=b.w;
    return f;
}

// LDS-only barrier (correctness proven r15-r20): orders LDS traffic without
// draining in-flight global loads/stores (T4).
__device__ __forceinline__ void bar_lds() {
    asm volatile("s_waitcnt lgkmcnt(0)" ::: "memory");
    __builtin_amdgcn_s_barrier();
    __builtin_amdgcn_sched_barrier(0);                  // rule-18 guard
}

// 256 blocks x 1024 thr (16 waves, 4/SIMD). Role split:
//   waves 0-3:  scan (Hloc = P@U), one iteration AHEAD (verbatim r20)
//   waves 4-11: Y = L@U + V@h_init, 2 chunks/barrier (verbatim r20);
//               waves 4-7 double as builders in the prologue
//   waves 12-15: DEDICATED STAGERS — prologue: chunks 0-7; loop iter k:
//               chunks 8+2k,9+2k (consumed at k+3 -> 3-barrier slack)
__global__ __launch_bounds__(1024) void ssm_one(const float* __restrict__ u,
                                                const float* __restrict__ A,
                                                const float* __restrict__ Bv,
                                                const float* __restrict__ Cv,
                                                float* __restrict__ y) {
    __shared__ short Ul[DT * UPAD];       // 65920 B: u row-block, bf16
    __shared__ short Pl[64 * PAD];        // 8704 B
    __shared__ short LV[2 * 64 * PAD];    // 17408 B: fp32 scratch, then L | V bf16
    __shared__ short Hl[2][2][DT * PAD];  // 8704 B: ring of h_init (buf x chunk-sub)
    __shared__ float kf[64];
    __shared__ float part[256];

    const int tid = threadIdx.x;
    const int bx  = blockIdx.x;           // 256 = b(4) * dt(64)
    const int dt  = bx & 63, b = bx >> 6;
    const int wid = tid >> 6;
    const int l   = tid & 63;
    const int lm  = l & 15, lq = l >> 4, lk8 = lq * 8;

    const float* ubase = u + ((size_t)(b * DM + dt * DT)) * LL;
    const int t2   = tid - 256;           // builder id (waves 4-7 in prologue)
    const int stid = tid - 768;           // stager id  (waves 12-15)

    // stager helper: stage chunks c0, c0+1 (512 float4, 2 per stager thread)
    auto stage2 = [&](int c0) {
#pragma unroll
        for (int i = 0; i < 2; ++i) {
            const int idx = stid + i * 256;           // 0..511
            const int r   = idx >> 5;                 // row 0..15
            const int tq  = (idx & 31) * 4 + c0 * TT; // 128 t covering 2 chunks
            const float4 v = *(const float4*)(ubase + (size_t)r * LL + tq);
            short4 h = make_short4((short)f2bf(v.x), (short)f2bf(v.y),
                                   (short)f2bf(v.z), (short)f2bf(v.w));
            *(short4*)&Ul[r * UPAD + tq] = h;
        }
    };

    // ---- phase 1: stagers chunks 0,1 || builders: P fill then scratch fill ----
    if (wid >= 12) {
        stage2(0);
    } else if (wid >= 4 && wid < 8) {
        // P[i][sigma] = Bv_i * a_i^(63-sigma)   (verbatim, verified)
        {
            const int i = t2 & 63, sq_ = t2 >> 6, q = 3 - sq_, s0 = sq_ * 16;
            const float a  = A[i * (NS + 1)];
            const float bv = Bv[i];
            const float a2 = a*a, a4 = a2*a2, a8 = a4*a4, a16 = a8*a8, a32 = a16*a16;
            float p = bv * ((q & 1) ? a16 : 1.f) * ((q & 2) ? a32 : 1.f);
#pragma unroll
            for (int jj = 15; jj >= 0; --jj) { Pl[i * PAD + s0 + jj] = (short)f2bf(p); p *= a; }
        }
        // scratch[delta][i] = w_i * a_i^delta   (verbatim, verified)
        {
            float* scr = (float*)LV;
            const int im = t2 & 63, dq = t2 >> 6, D0 = dq * 16;
            const float a  = A[im * (NS + 1)];
            const float wv = Bv[im] * Cv[im];
            const float a2 = a*a, a4 = a2*a2, a8 = a4*a4, a16 = a8*a8, a32 = a16*a16;
            float p = wv * ((dq & 1) ? a16 : 1.f) * ((dq & 2) ? a32 : 1.f);
#pragma unroll
            for (int dd = 0; dd < 16; ++dd) { scr[(D0 + dd) * PAD + im] = p; p *= a; }
        }
    }
    bar_lds();

    // ---- phase 2: stagers chunks 2,3 || builders: part reduce ----
    if (wid >= 12) {
        stage2(2);
    } else if (wid >= 4 && wid < 8) {
        float* scr = (float*)LV;
        const int Dl = t2 & 63, q = t2 >> 6;
        float ssum = 0.f;
#pragma unroll
        for (int ii = 0; ii < 16; ++ii) ssum += scr[Dl * PAD + q * 16 + ii];
        part[t2] = ssum;
    }
    bar_lds();

    // ---- phase 3: stagers chunks 4,5 || builders: kf ----
    if (wid >= 12) {
        stage2(4);
    } else if (wid >= 4 && wid < 8 && t2 < 64) {
        kf[t2] = part[t2] + part[t2 + 64] + part[t2 + 128] + part[t2 + 192];
    }
    bar_lds();

    // ---- phase 4: stagers chunks 6,7 || builders: L, V fill ----
    if (wid >= 12) {
        stage2(6);
    } else if (wid >= 4 && wid < 8) {
        short* Ll = LV;                               // L: lower-tri Toeplitz of kf
        const int r = t2 >> 2, sb = (t2 & 3) * 16;
#pragma unroll
        for (int s2 = 0; s2 < 16; ++s2) {
            const int sc = sb + s2;
            Ll[r * PAD + sc] = (r >= sc) ? (short)f2bf(kf[r - sc]) : (short)0;
        }
        short* Vl = LV + 64 * PAD;                    // V[r][i] = C_i a_i^(r+1)
        const int im = t2 & 63, rq = t2 >> 6, r0 = rq * 16;
        const float a  = A[im * (NS + 1)];
        const float cv = Cv[im];
        const float a2 = a*a, a4 = a2*a2, a8 = a4*a4, a16 = a8*a8, a32 = a16*a16;
        float p = cv * a * ((rq & 1) ? a16 : 1.f) * ((rq & 2) ? a32 : 1.f);
#pragma unroll
        for (int rr = 0; rr < 16; ++rr) { Vl[(r0 + rr) * PAD + im] = (short)f2bf(p); p *= a; }
    }
    bar_lds();

    // ---- per-wave invariant fragments + scan state (verbatim r20) ----
    bf8 fA0, fA1, fB0, fB1;
    float aT[4];
    f32x4 hrun = (f32x4){0.f, 0.f, 0.f, 0.f};
    if (wid < 4) {
        fA0 = ld_frag(&Pl[(wid * 16 + lm) * PAD + lk8]);
        fA1 = ld_frag(&Pl[(wid * 16 + lm) * PAD + 32 + lk8]);
        fB0 = fA0; fB1 = fA1;   // unused
#pragma unroll
        for (int r = 0; r < 4; ++r) {       // aT = a_i^64 for my 4 acc rows
            const int i = wid * 16 + lq * 4 + r;
            float x = A[i * (NS + 1)];
#pragma unroll
            for (int q = 0; q < 6; ++q) x = x * x;
            aT[r] = x;
        }
    } else if (wid < 12) {
        const int wt = (wid - 4) & 3;
        fA0 = ld_frag(&LV[(wt * 16 + lm) * PAD + lk8]);              // L
        fA1 = ld_frag(&LV[(wt * 16 + lm) * PAD + 32 + lk8]);
        fB0 = ld_frag(&LV[64 * PAD + (wt * 16 + lm) * PAD + lk8]);   // V
        fB1 = ld_frag(&LV[64 * PAD + (wt * 16 + lm) * PAD + 32 + lk8]);
        aT[0] = aT[1] = aT[2] = aT[3] = 0.f;
    } else {
        aT[0] = aT[1] = aT[2] = aT[3] = 0.f;
    }

    // ---- scan prologue: chunks 0,1 -> Hl[0][0..1] ----
    if (wid < 4) {
        const int i0 = wid * 16 + lq * 4;
#pragma unroll
        for (int s = 0; s < 2; ++s) {
            short4 hh = make_short4((short)f2bf(hrun[0]), (short)f2bf(hrun[1]),
                                    (short)f2bf(hrun[2]), (short)f2bf(hrun[3]));
            *(short4*)&Hl[0][s][lm * PAD + i0] = hh;
            const int tb = s * TT;
            const bf8 bU0 = ld_frag(&Ul[lm * UPAD + tb + lk8]);
            const bf8 bU1 = ld_frag(&Ul[lm * UPAD + tb + 32 + lk8]);
            f32x4 hl = (f32x4){0.f, 0.f, 0.f, 0.f};
            hl = __builtin_amdgcn_mfma_f32_16x16x32_bf16(fA0, bU0, hl, 0, 0, 0);
            hl = __builtin_amdgcn_mfma_f32_16x16x32_bf16(fA1, bU1, hl, 0, 0, 0);
#pragma unroll
            for (int r = 0; r < 4; ++r) hrun[r] = fmaf(aT[r], hrun[r], hl[r]);
        }
    }
    bar_lds();

    // ---- main loop: 16 iterations, 2 chunks each, 1 LDS-only barrier each ----
    for (int k = 0; k < 16; ++k) {
        if (wid >= 12) {
            // stagers: chunks 8+2k, 9+2k (consumed by scan at k+3)
            if (k < 12) stage2(8 + 2 * k);
        } else if (wid < 4) {
            // scan one iteration ahead: chunks 2k+2, 2k+3 -> Hl[(k+1)&1]
            const int c2 = 2 * k + 2;
            if (c2 < CC) {
                const int i0 = wid * 16 + lq * 4;
#pragma unroll
                for (int s = 0; s < 2; ++s) {
                    short4 hh = make_short4((short)f2bf(hrun[0]), (short)f2bf(hrun[1]),
                                            (short)f2bf(hrun[2]), (short)f2bf(hrun[3]));
                    *(short4*)&Hl[(k + 1) & 1][s][lm * PAD + i0] = hh;
                    const int tb = (c2 + s) * TT;
                    const bf8 bU0 = ld_frag(&Ul[lm * UPAD + tb + lk8]);
                    const bf8 bU1 = ld_frag(&Ul[lm * UPAD + tb + 32 + lk8]);
                    f32x4 hl = (f32x4){0.f, 0.f, 0.f, 0.f};
                    hl = __builtin_amdgcn_mfma_f32_16x16x32_bf16(fA0, bU0, hl, 0, 0, 0);
                    hl = __builtin_amdgcn_mfma_f32_16x16x32_bf16(fA1, bU1, hl, 0, 0, 0);
#pragma unroll
                    for (int r = 0; r < 4; ++r) hrun[r] = fmaf(aT[r], hrun[r], hl[r]);
                }
            }
        } else {
            // Y waves: chunk c = 2k + sub, h_init from Hl[k&1][sub]
            const int sub = (wid - 4) >> 2;
            const int wt  = (wid - 4) & 3;
            const int c   = 2 * k + sub;
            const int tb  = c * TT;
            const bf8 bU0 = ld_frag(&Ul[lm * UPAD + tb + lk8]);
            const bf8 bU1 = ld_frag(&Ul[lm * UPAD + tb + 32 + lk8]);
            const bf8 bH0 = ld_frag(&Hl[k & 1][sub][lm * PAD + lk8]);
            const bf8 bH1 = ld_frag(&Hl[k & 1][sub][lm * PAD + 32 + lk8]);
            f32x4 yac = (f32x4){0.f, 0.f, 0.f, 0.f};
            yac = __builtin_amdgcn_mfma_f32_16x16x32_bf16(fA0, bU0, yac, 0, 0, 0);
            yac = __builtin_amdgcn_mfma_f32_16x16x32_bf16(fA1, bU1, yac, 0, 0, 0);
            yac = __builtin_amdgcn_mfma_f32_16x16x32_bf16(fB0, bH0, yac, 0, 0, 0);
            yac = __builtin_amdgcn_mfma_f32_16x16x32_bf16(fB1, bH1, yac, 0, 0, 0);
            const int t0 = tb + wt * 16 + lq * 4;     // C rows = t (contiguous 4)
            *(f32x4*)&y[((size_t)(b * DM + dt * DT + lm)) * LL + t0] = yac;
        }
        bar_lds();
    }
}

extern "C" void kernel_launch(void* const* d_in, const int* in_sizes, int n_in,
                              void* d_out, int out_size, void* d_ws, size_t ws_size,
                              hipStream_t stream) {
    const float* u  = (const float*)d_in[0];
    const float* A  = (const float*)d_in[1];
    const float* Bv = (const float*)d_in[2];
    const float* Cv = (const float*)d_in[3];
    float* y = (float*)d_out;

    ssm_one<<<BS * (DM / DT), 1024, 0, stream>>>(u, A, Bv, Cv, y);
}

// Round 22
// 21.559 us; speedup vs baseline: 1.0874x; 1.0874x over previous
//
#include <hip/hip_runtime.h>

#define BS 4
#define DM 1024
#define LL 2048
#define NS 64
#define CC 32        // chunks
#define TT 64        // chunk length
#define PAD 68       // LDS row stride for 64-wide mats (136B -> conflict-light)
#define UPAD 2060    // U row stride (shorts): dword stride 1030 -> spread banks
#define DT 16        // d-rows per block

typedef __attribute__((ext_vector_type(8))) short bf8;     // 8 bf16 (4 VGPR)
typedef __attribute__((ext_vector_type(4))) float f32x4;   // mfma C/D

__device__ __forceinline__ unsigned short f2bf(float x) {  // fp32 -> bf16 RNE
    unsigned u = __float_as_uint(x);
    return (unsigned short)((u + 0x7FFFu + ((u >> 16) & 1u)) >> 16);
}

__device__ __forceinline__ bf8 ld_frag(const short* p) {   // 8 contiguous bf16 (8B aligned)
    short4 a = *(const short4*)p;
    short4 b = *(const short4*)(p + 4);
    bf8 f;
    f[0]=a.x; f[1]=a.y; f[2]=a.z; f[3]=a.w;
    f[4]=b.x; f[5]=b.y; f[6]=b.z; f[7]=b.w;
    return f;
}

// LDS-only barrier (correctness proven r15-r21): orders LDS traffic without
// draining in-flight global loads/stores (T4).
__device__ __forceinline__ void bar_lds() {
    asm volatile("s_waitcnt lgkmcnt(0)" ::: "memory");
    __builtin_amdgcn_s_barrier();
    __builtin_amdgcn_sched_barrier(0);                  // rule-18 guard
}

// FINAL (r20 verbatim, best measured: 21.53us).
// 256 blocks (b x 16-d tile) x 768 thr (12 waves, 3/SIMD).
//   waves 0-7 (512 thr): stage U in 4 t-major batches
//   waves 8-11 (256 thr): P -> scratch -> kf-reduce -> L,V builder chain
// then: waves 0-3 scan (one iteration ahead), waves 4-11 Y, 2 chunks/barrier.
__global__ __launch_bounds__(768) void ssm_one(const float* __restrict__ u,
                                               const float* __restrict__ A,
                                               const float* __restrict__ Bv,
                                               const float* __restrict__ Cv,
                                               float* __restrict__ y) {
    __shared__ short Ul[DT * UPAD];       // 65920 B: u row-block, bf16
    __shared__ short Pl[64 * PAD];        // 8704 B
    __shared__ short LV[2 * 64 * PAD];    // 17408 B: fp32 scratch, then L | V bf16
    __shared__ short Hl[2][2][DT * PAD];  // 8704 B: ring of h_init (buf x chunk-sub)
    __shared__ float kf[64];
    __shared__ float part[256];

    const int tid = threadIdx.x;
    const int bx  = blockIdx.x;           // 256 = b(4) * dt(64)
    const int dt  = bx & 63, b = bx >> 6;
    const int wid = tid >> 6;
    const int l   = tid & 63;
    const int lm  = l & 15, lq = l >> 4, lk8 = lq * 8;

    const float* ubase = u + ((size_t)(b * DM + dt * DT)) * LL;
    const bool stager = (tid < 512);
    const int  t2     = tid - 512;        // builder thread id (waves 8-11)

    // staging helper: batch j stages t-range [512j, 512j+512) of all 16 rows
    auto stage_batch = [&](int j) {
#pragma unroll
        for (int i = 0; i < 4; ++i) {
            const int s  = tid + i * 512;           // 0..2047
            const int r  = s >> 7;                  // row 0..15
            const int tq = (s & 127) * 4 + j * 512; // 32 lanes -> 512B contiguous
            const float4 v = *(const float4*)(ubase + (size_t)r * LL + tq);
            short4 h = make_short4((short)f2bf(v.x), (short)f2bf(v.y),
                                   (short)f2bf(v.z), (short)f2bf(v.w));
            *(short4*)&Ul[r * UPAD + tq] = h;
        }
    };

    // ---- phase 1: stagers batch 0  ||  builders: P fill then scratch fill ----
    if (stager) {
        stage_batch(0);
    } else {
        // P[i][sigma] = Bv_i * a_i^(63-sigma)   (verbatim, verified)
        {
            const int i = t2 & 63, sq_ = t2 >> 6, q = 3 - sq_, s0 = sq_ * 16;
            const float a  = A[i * (NS + 1)];
            const float bv = Bv[i];
            const float a2 = a*a, a4 = a2*a2, a8 = a4*a4, a16 = a8*a8, a32 = a16*a16;
            float p = bv * ((q & 1) ? a16 : 1.f) * ((q & 2) ? a32 : 1.f);
#pragma unroll
            for (int jj = 15; jj >= 0; --jj) { Pl[i * PAD + s0 + jj] = (short)f2bf(p); p *= a; }
        }
        // scratch[delta][i] = w_i * a_i^delta   (verbatim, verified)
        {
            float* scr = (float*)LV;
            const int im = t2 & 63, dq = t2 >> 6, D0 = dq * 16;
            const float a  = A[im * (NS + 1)];
            const float wv = Bv[im] * Cv[im];
            const float a2 = a*a, a4 = a2*a2, a8 = a4*a4, a16 = a8*a8, a32 = a16*a16;
            float p = wv * ((dq & 1) ? a16 : 1.f) * ((dq & 2) ? a32 : 1.f);
#pragma unroll
            for (int dd = 0; dd < 16; ++dd) { scr[(D0 + dd) * PAD + im] = p; p *= a; }
        }
    }
    bar_lds();

    // ---- phase 2: stagers batch 1  ||  builders: part reduce ----
    if (stager) {
        stage_batch(1);
    } else {
        float* scr = (float*)LV;
        const int Dl = t2 & 63, q = t2 >> 6;
        float ssum = 0.f;
#pragma unroll
        for (int ii = 0; ii < 16; ++ii) ssum += scr[Dl * PAD + q * 16 + ii];
        part[t2] = ssum;
    }
    bar_lds();

    // ---- phase 3: stagers batch 2  ||  builders: kf ----
    if (stager) {
        stage_batch(2);
    } else if (t2 < 64) {
        kf[t2] = part[t2] + part[t2 + 64] + part[t2 + 128] + part[t2 + 192];
    }
    bar_lds();

    // ---- phase 4: stagers batch 3  ||  builders: L, V fill ----
    if (stager) {
        stage_batch(3);
    } else {
        short* Ll = LV;                               // L: lower-tri Toeplitz of kf
        const int r = t2 >> 2, sb = (t2 & 3) * 16;
#pragma unroll
        for (int s2 = 0; s2 < 16; ++s2) {
            const int sc = sb + s2;
            Ll[r * PAD + sc] = (r >= sc) ? (short)f2bf(kf[r - sc]) : (short)0;
        }
        short* Vl = LV + 64 * PAD;                    // V[r][i] = C_i a_i^(r+1)
        const int im = t2 & 63, rq = t2 >> 6, r0 = rq * 16;
        const float a  = A[im * (NS + 1)];
        const float cv = Cv[im];
        const float a2 = a*a, a4 = a2*a2, a8 = a4*a4, a16 = a8*a8, a32 = a16*a16;
        float p = cv * a * ((rq & 1) ? a16 : 1.f) * ((rq & 2) ? a32 : 1.f);
#pragma unroll
        for (int rr = 0; rr < 16; ++rr) { Vl[(r0 + rr) * PAD + im] = (short)f2bf(p); p *= a; }
    }
    bar_lds();

    // ---- per-wave invariant fragments + scan state ----
    bf8 fA0, fA1, fB0, fB1;
    float aT[4];
    f32x4 hrun = (f32x4){0.f, 0.f, 0.f, 0.f};
    if (wid < 4) {
        fA0 = ld_frag(&Pl[(wid * 16 + lm) * PAD + lk8]);
        fA1 = ld_frag(&Pl[(wid * 16 + lm) * PAD + 32 + lk8]);
        fB0 = fA0; fB1 = fA1;   // unused
#pragma unroll
        for (int r = 0; r < 4; ++r) {       // aT = a_i^64 for my 4 acc rows
            const int i = wid * 16 + lq * 4 + r;
            float x = A[i * (NS + 1)];
#pragma unroll
            for (int q = 0; q < 6; ++q) x = x * x;
            aT[r] = x;
        }
    } else {
        const int wt = (wid - 4) & 3;
        fA0 = ld_frag(&LV[(wt * 16 + lm) * PAD + lk8]);              // L
        fA1 = ld_frag(&LV[(wt * 16 + lm) * PAD + 32 + lk8]);
        fB0 = ld_frag(&LV[64 * PAD + (wt * 16 + lm) * PAD + lk8]);   // V
        fB1 = ld_frag(&LV[64 * PAD + (wt * 16 + lm) * PAD + 32 + lk8]);
        aT[0] = aT[1] = aT[2] = aT[3] = 0.f;
    }

    // ---- scan prologue: chunks 0,1 -> Hl[0][0..1] ----
    if (wid < 4) {
        const int i0 = wid * 16 + lq * 4;
#pragma unroll
        for (int s = 0; s < 2; ++s) {
            short4 hh = make_short4((short)f2bf(hrun[0]), (short)f2bf(hrun[1]),
                                    (short)f2bf(hrun[2]), (short)f2bf(hrun[3]));
            *(short4*)&Hl[0][s][lm * PAD + i0] = hh;
            const int tb = s * TT;
            const bf8 bU0 = ld_frag(&Ul[lm * UPAD + tb + lk8]);
            const bf8 bU1 = ld_frag(&Ul[lm * UPAD + tb + 32 + lk8]);
            f32x4 hl = (f32x4){0.f, 0.f, 0.f, 0.f};
            hl = __builtin_amdgcn_mfma_f32_16x16x32_bf16(fA0, bU0, hl, 0, 0, 0);
            hl = __builtin_amdgcn_mfma_f32_16x16x32_bf16(fA1, bU1, hl, 0, 0, 0);
#pragma unroll
            for (int r = 0; r < 4; ++r) hrun[r] = fmaf(aT[r], hrun[r], hl[r]);
        }
    }
    bar_lds();

    // ---- main loop: 16 iterations, 2 chunks each, 1 LDS-only barrier each ----
    for (int k = 0; k < 16; ++k) {
        if (wid < 4) {
            // scan one iteration ahead: chunks 2k+2, 2k+3 -> Hl[(k+1)&1]
            const int c2 = 2 * k + 2;
            if (c2 < CC) {
                const int i0 = wid * 16 + lq * 4;
#pragma unroll
                for (int s = 0; s < 2; ++s) {
                    short4 hh = make_short4((short)f2bf(hrun[0]), (short)f2bf(hrun[1]),
                                            (short)f2bf(hrun[2]), (short)f2bf(hrun[3]));
                    *(short4*)&Hl[(k + 1) & 1][s][lm * PAD + i0] = hh;
                    const int tb = (c2 + s) * TT;
                    const bf8 bU0 = ld_frag(&Ul[lm * UPAD + tb + lk8]);
                    const bf8 bU1 = ld_frag(&Ul[lm * UPAD + tb + 32 + lk8]);
                    f32x4 hl = (f32x4){0.f, 0.f, 0.f, 0.f};
                    hl = __builtin_amdgcn_mfma_f32_16x16x32_bf16(fA0, bU0, hl, 0, 0, 0);
                    hl = __builtin_amdgcn_mfma_f32_16x16x32_bf16(fA1, bU1, hl, 0, 0, 0);
#pragma unroll
                    for (int r = 0; r < 4; ++r) hrun[r] = fmaf(aT[r], hrun[r], hl[r]);
                }
            }
        } else {
            // Y waves: chunk c = 2k + sub, h_init from Hl[k&1][sub]
            const int sub = (wid - 4) >> 2;
            const int wt  = (wid - 4) & 3;
            const int c   = 2 * k + sub;
            const int tb  = c * TT;
            const bf8 bU0 = ld_frag(&Ul[lm * UPAD + tb + lk8]);
            const bf8 bU1 = ld_frag(&Ul[lm * UPAD + tb + 32 + lk8]);
            const bf8 bH0 = ld_frag(&Hl[k & 1][sub][lm * PAD + lk8]);
            const bf8 bH1 = ld_frag(&Hl[k & 1][sub][lm * PAD + 32 + lk8]);
            f32x4 yac = (f32x4){0.f, 0.f, 0.f, 0.f};
            yac = __builtin_amdgcn_mfma_f32_16x16x32_bf16(fA0, bU0, yac, 0, 0, 0);
            yac = __builtin_amdgcn_mfma_f32_16x16x32_bf16(fA1, bU1, yac, 0, 0, 0);
            yac = __builtin_amdgcn_mfma_f32_16x16x32_bf16(fB0, bH0, yac, 0, 0, 0);
            yac = __builtin_amdgcn_mfma_f32_16x16x32_bf16(fB1, bH1, yac, 0, 0, 0);
            const int t0 = tb + wt * 16 + lq * 4;     // C rows = t (contiguous 4)
            *(f32x4*)&y[((size_t)(b * DM + dt * DT + lm)) * LL + t0] = yac;
        }
        bar_lds();
    }
}

extern "C" void kernel_launch(void* const* d_in, const int* in_sizes, int n_in,
                              void* d_out, int out_size, void* d_ws, size_t ws_size,
                              hipStream_t stream) {
    const float* u  = (const float*)d_in[0];
    const float* A  = (const float*)d_in[1];
    const float* Bv = (const float*)d_in[2];
    const float* Cv = (const float*)d_in[3];
    float* y = (float*)d_out;

    ssm_one<<<BS * (DM / DT), 768, 0, stream>>>(u, A, Bv, Cv, y);
}